// Round 12
// baseline (745.663 us; speedup 1.0000x reference)
//
#include <hip/hip_runtime.h>

typedef __attribute__((ext_vector_type(8))) short bf16x8;
typedef __attribute__((ext_vector_type(4))) float f32x4;
typedef __attribute__((ext_vector_type(4))) unsigned short u16x4;

__device__ __forceinline__ float bf2f(unsigned short h) {
  return __uint_as_float(((unsigned)h) << 16);
}
// packed fp32->bf16 (RTNE)
__device__ __forceinline__ unsigned cvtpk(float a, float b) {
  unsigned r;
  asm("v_cvt_pk_bf16_f32 %0, %1, %2" : "=v"(r) : "v"(a), "v"(b));
  return r;
}
__device__ __forceinline__ unsigned short f2bf(float f) {
  return (unsigned short)(cvtpk(f, f) & 0xffffu);
}
__device__ __forceinline__ bf16x8 pack8(f32x4 x0, f32x4 x1) {
  union { bf16x8 v; unsigned u[4]; } z;
  z.u[0] = cvtpk(x0[0], x0[1]);
  z.u[1] = cvtpk(x0[2], x0[3]);
  z.u[2] = cvtpk(x1[0], x1[1]);
  z.u[3] = cvtpk(x1[2], x1[3]);
  return z.v;
}

// ---------------- GEMM64: out[M,64] = A[M,64] @ W[64,64] + b ----------------
template<bool IN_BF16, bool OUT_BF16>
__device__ __forceinline__ void gemm64_body(const void* __restrict__ Ain,
    const float* __restrict__ W, const float* __restrict__ bias,
    void* __restrict__ Out, int M, int wid, int nw, int tid) {
  const int l = tid & 63;
  const int g = l >> 4;
  const int n15 = l & 15;

  bf16x8 bfrag[4][2];
  float bv[4];
#pragma unroll
  for (int nb = 0; nb < 4; ++nb) {
    bv[nb] = bias[nb * 16 + n15];
#pragma unroll
    for (int kb = 0; kb < 2; ++kb)
#pragma unroll
      for (int j = 0; j < 8; ++j)
        bfrag[nb][kb][j] = (short)f2bf(W[(kb * 32 + g * 8 + j) * 64 + nb * 16 + n15]);
  }

  int ntiles = (M + 15) >> 4;
  for (int t = wid; t < ntiles; t += nw) {
    int m0 = t << 4;
    int arow = m0 + n15;
    bf16x8 a0, a1;
    if (arow < M) {
      if constexpr (IN_BF16) {
        const unsigned short* ap = (const unsigned short*)Ain + (size_t)arow * 64 + g * 8;
        a0 = *(const bf16x8*)ap;
        a1 = *(const bf16x8*)(ap + 32);
      } else {
        const float* ap = (const float*)Ain + (size_t)arow * 64 + g * 8;
        a0 = pack8(*(const f32x4*)ap, *(const f32x4*)(ap + 4));
        a1 = pack8(*(const f32x4*)(ap + 32), *(const f32x4*)(ap + 36));
      }
    } else {
#pragma unroll
      for (int j = 0; j < 8; ++j) { a0[j] = 0; a1[j] = 0; }
    }
    f32x4 acc[4];
#pragma unroll
    for (int nb = 0; nb < 4; ++nb) {
      acc[nb] = (f32x4){bv[nb], bv[nb], bv[nb], bv[nb]};
      acc[nb] = __builtin_amdgcn_mfma_f32_16x16x32_bf16(a0, bfrag[nb][0], acc[nb], 0, 0, 0);
      acc[nb] = __builtin_amdgcn_mfma_f32_16x16x32_bf16(a1, bfrag[nb][1], acc[nb], 0, 0, 0);
    }
#pragma unroll
    for (int nb = 0; nb < 4; ++nb)
#pragma unroll
      for (int r = 0; r < 4; ++r) {
        int orow = m0 + g * 4 + r;
        if (orow < M) {
          float val = acc[nb][r];
          size_t oidx = (size_t)orow * 64 + nb * 16 + n15;
          if constexpr (OUT_BF16) ((unsigned short*)Out)[oidx] = f2bf(val);
          else                    ((float*)Out)[oidx] = val;
        }
      }
  }
}

template<bool IN_BF16, bool OUT_BF16>
__global__ void __launch_bounds__(256) gemm64_kernel(const void* __restrict__ Ain,
    const float* __restrict__ W, const float* __restrict__ bias,
    void* __restrict__ Out, int M) {
  int wid = (blockIdx.x * blockDim.x + threadIdx.x) >> 6;
  int nw = (gridDim.x * blockDim.x) >> 6;
  gemm64_body<IN_BF16, OUT_BF16>(Ain, W, bias, Out, M, wid, nw, threadIdx.x);
}

// Fused q/k/v: 3 weight sets resident, hx read once, bf16 outputs.
__global__ void __launch_bounds__(256) qkv3_kernel(const float* __restrict__ hx,
    const float* __restrict__ Wq, const float* __restrict__ bq,
    const float* __restrict__ Wk, const float* __restrict__ bk,
    const float* __restrict__ Wv, const float* __restrict__ bv,
    unsigned short* __restrict__ q, unsigned short* __restrict__ k,
    unsigned short* __restrict__ v, int M) {
  const int tid = threadIdx.x;
  const int l = tid & 63;
  const int g = l >> 4;
  const int n15 = l & 15;
  const float* Ws[3] = {Wq, Wk, Wv};
  const float* bs[3] = {bq, bk, bv};
  unsigned short* outs[3] = {q, k, v};

  bf16x8 bfrag[3][4][2];
  float bvv[3][4];
#pragma unroll
  for (int w = 0; w < 3; ++w)
#pragma unroll
    for (int nb = 0; nb < 4; ++nb) {
      bvv[w][nb] = bs[w][nb * 16 + n15];
#pragma unroll
      for (int kb = 0; kb < 2; ++kb)
#pragma unroll
        for (int j = 0; j < 8; ++j)
          bfrag[w][nb][kb][j] = (short)f2bf(Ws[w][(kb * 32 + g * 8 + j) * 64 + nb * 16 + n15]);
    }

  int wid = (blockIdx.x * blockDim.x + tid) >> 6;
  int nw = (gridDim.x * blockDim.x) >> 6;
  int ntiles = (M + 15) >> 4;
  for (int t = wid; t < ntiles; t += nw) {
    int m0 = t << 4;
    int arow = m0 + n15;
    bf16x8 a0, a1;
    if (arow < M) {
      const float* ap = hx + (size_t)arow * 64 + g * 8;
      a0 = pack8(*(const f32x4*)ap, *(const f32x4*)(ap + 4));
      a1 = pack8(*(const f32x4*)(ap + 32), *(const f32x4*)(ap + 36));
    } else {
#pragma unroll
      for (int j = 0; j < 8; ++j) { a0[j] = 0; a1[j] = 0; }
    }
#pragma unroll
    for (int w = 0; w < 3; ++w) {
      f32x4 acc[4];
#pragma unroll
      for (int nb = 0; nb < 4; ++nb) {
        acc[nb] = (f32x4){bvv[w][nb], bvv[w][nb], bvv[w][nb], bvv[w][nb]};
        acc[nb] = __builtin_amdgcn_mfma_f32_16x16x32_bf16(a0, bfrag[w][nb][0], acc[nb], 0, 0, 0);
        acc[nb] = __builtin_amdgcn_mfma_f32_16x16x32_bf16(a1, bfrag[w][nb][1], acc[nb], 0, 0, 0);
      }
#pragma unroll
      for (int nb = 0; nb < 4; ++nb)
#pragma unroll
        for (int r = 0; r < 4; ++r) {
          int orow = m0 + g * 4 + r;
          if (orow < M)
            outs[w][(size_t)orow * 64 + nb * 16 + n15] = f2bf(acc[nb][r]);
        }
    }
  }
}

// WeM[d][h] = sum_m We[d][m*8+h] * (1/sqrt(8)); beM[h] likewise from be.
__global__ void wemprep_kernel(const float* __restrict__ We, const float* __restrict__ be,
                               float* __restrict__ WeM, float* __restrict__ beM) {
  int tid = threadIdx.x;
  if (tid < 512) {
    int d = tid >> 3, h = tid & 7;
    float s = 0.f;
#pragma unroll
    for (int m = 0; m < 8; ++m) s += We[d * 64 + m * 8 + h];
    WeM[d * 8 + h] = s * 0.35355339059327373f;
  }
  if (tid < 8) {
    float s = 0.f;
#pragma unroll
    for (int m = 0; m < 8; ++m) s += be[tid + m * 8];
    beM[tid] = s * 0.35355339059327373f;
  }
}

// ---------------- Fused edge pipeline v4: all-MFMA, zero LDS, minimal shfl ----------
// gate = he@WeM + beM (C-layout: row=edge g*4+r, col=head n15, n15<8)
// p    = (q[row]⊙k[col]) @ Mask   (Mask[c][h]=[c&7==h]; same C-layout as gate)
// s    = p*gate (1/sqrt8 folded in WeM/beM); escores[slot] = s; feat = s*elin -> global
__global__ void __launch_bounds__(256) edge_fused_kernel(
    const float* __restrict__ he,
    const int* __restrict__ rowi, const int* __restrict__ coli,
    const int* __restrict__ eslot,
    const unsigned short* __restrict__ qb, const unsigned short* __restrict__ kbuf,
    const float* __restrict__ We, const float* __restrict__ be,
    const float* __restrict__ WeM, const float* __restrict__ beM,
    unsigned short* __restrict__ feat, float* __restrict__ escores, int E) {
  const int tid = threadIdx.x;
  const int l = tid & 63;
  const int g = l >> 4;
  const int n15 = l & 15;

  // resident B-frags: We (32 VGPR), WeM gate (8), mask (4)
  bf16x8 bfE[4][2];
  float beV[4];
#pragma unroll
  for (int nb = 0; nb < 4; ++nb) {
    beV[nb] = be[nb * 16 + n15];
#pragma unroll
    for (int kb = 0; kb < 2; ++kb)
#pragma unroll
      for (int j = 0; j < 8; ++j)
        bfE[nb][kb][j] = (short)f2bf(We[(kb * 32 + g * 8 + j) * 64 + nb * 16 + n15]);
  }
  bf16x8 gB0, gB1, mB;
  const bool hv = (n15 < 8);
#pragma unroll
  for (int j = 0; j < 8; ++j) {
    gB0[j] = hv ? (short)f2bf(WeM[(g * 8 + j) * 8 + n15]) : (short)0;
    gB1[j] = hv ? (short)f2bf(WeM[(32 + g * 8 + j) * 8 + n15]) : (short)0;
    mB[j]  = (hv && j == n15) ? (short)0x3F80 : (short)0;  // bf16 1.0
  }
  const float beMv = hv ? beM[n15] : 0.f;

  const int ntiles = (E + 15) >> 4;
  int wid = (blockIdx.x * blockDim.x + tid) >> 6;
  int nw = (gridDim.x * blockDim.x) >> 6;
  for (int t = wid; t < ntiles; t += nw) {
    const int m0 = t << 4;
    const int es = min(m0 + n15, E - 1);  // clamp -> dup rows; stores guarded
    const int rq = rowi[es], rc = coli[es], sl = eslot[es];

    // he A-frags
    const float* ap = he + (size_t)es * 64 + g * 8;
    bf16x8 a0 = pack8(*(const f32x4*)ap, *(const f32x4*)(ap + 4));
    bf16x8 a1 = pack8(*(const f32x4*)(ap + 32), *(const f32x4*)(ap + 36));

    // q/k in A-frag layout (lane: row es, cols g*8..+7 and 32+g*8..+7)
    const unsigned short* qp = qb + (size_t)rq * 64 + g * 8;
    const unsigned short* kp = kbuf + (size_t)rc * 64 + g * 8;
    bf16x8 qv0 = *(const bf16x8*)qp, qv1 = *(const bf16x8*)(qp + 32);
    bf16x8 kv0 = *(const bf16x8*)kp, kv1 = *(const bf16x8*)(kp + 32);

    // elin (C-layout) + gate (C-layout col=head)
    f32x4 acc[4];
#pragma unroll
    for (int nb = 0; nb < 4; ++nb) {
      acc[nb] = (f32x4){beV[nb], beV[nb], beV[nb], beV[nb]};
      acc[nb] = __builtin_amdgcn_mfma_f32_16x16x32_bf16(a0, bfE[nb][0], acc[nb], 0, 0, 0);
      acc[nb] = __builtin_amdgcn_mfma_f32_16x16x32_bf16(a1, bfE[nb][1], acc[nb], 0, 0, 0);
    }
    f32x4 gate = (f32x4){beMv, beMv, beMv, beMv};
    gate = __builtin_amdgcn_mfma_f32_16x16x32_bf16(a0, gB0, gate, 0, 0, 0);
    gate = __builtin_amdgcn_mfma_f32_16x16x32_bf16(a1, gB1, gate, 0, 0, 0);

    // qk elementwise product -> bf16 A-frags -> masked MFMA = per-head dots
    f32x4 pr0a, pr0b, pr1a, pr1b;
#pragma unroll
    for (int j = 0; j < 4; ++j) {
      pr0a[j] = bf2f((unsigned short)qv0[j]) * bf2f((unsigned short)kv0[j]);
      pr0b[j] = bf2f((unsigned short)qv0[4 + j]) * bf2f((unsigned short)kv0[4 + j]);
      pr1a[j] = bf2f((unsigned short)qv1[j]) * bf2f((unsigned short)kv1[j]);
      pr1b[j] = bf2f((unsigned short)qv1[4 + j]) * bf2f((unsigned short)kv1[4 + j]);
    }
    bf16x8 pa0 = pack8(pr0a, pr0b), pa1 = pack8(pr1a, pr1b);
    f32x4 p = (f32x4){0.f, 0.f, 0.f, 0.f};
    p = __builtin_amdgcn_mfma_f32_16x16x32_bf16(pa0, mB, p, 0, 0, 0);
    p = __builtin_amdgcn_mfma_f32_16x16x32_bf16(pa1, mB, p, 0, 0, 0);

    // s = p*gate (valid at n15<8; zero elsewhere), write escores in CSR slot order
    float s_[4];
#pragma unroll
    for (int r = 0; r < 4; ++r) s_[r] = p[r] * gate[r];
#pragma unroll
    for (int r = 0; r < 4; ++r) {
      int slot = __shfl(sl, g * 4 + r, 64);
      if (hv && m0 + g * 4 + r < E) escores[(size_t)slot * 8 + n15] = s_[r];
    }
    // spread s to upper half-lanes (head = n15&7)
#pragma unroll
    for (int r = 0; r < 4; ++r) {
      float o = __shfl_xor(s_[r], 8, 64);
      if (!hv) s_[r] = o;
    }
    // feat = s*elin -> global bf16 (C-layout coalesced-ish stores)
#pragma unroll
    for (int nb = 0; nb < 4; ++nb)
#pragma unroll
      for (int r = 0; r < 4; ++r) {
        int orow = m0 + g * 4 + r;
        if (orow < E) feat[(size_t)orow * 64 + nb * 16 + n15] = f2bf(s_[r] * acc[nb][r]);
      }
  }
}

// ---------------- CSR build ----------------
__global__ void zero_kernel(int* __restrict__ p, int n) {
  int i = blockIdx.x * blockDim.x + threadIdx.x;
  if (i < n) p[i] = 0;
}

__global__ void hist_kernel(const int* __restrict__ row, int* __restrict__ deg, int E) {
  int gid = blockIdx.x * blockDim.x + threadIdx.x;
  if (gid < E) atomicAdd(&deg[row[gid]], 1);
}

#define SCAN_B 256
#define SCAN_E 8
__global__ void scan1_kernel(const int* __restrict__ deg, int* __restrict__ rowptr,
                             int* __restrict__ blksum, int n) {
  __shared__ int sh[SCAN_B];
  int base = blockIdx.x * (SCAN_B * SCAN_E) + threadIdx.x * SCAN_E;
  int v[SCAN_E];
  int s = 0;
#pragma unroll
  for (int j = 0; j < SCAN_E; ++j) {
    v[j] = (base + j < n) ? deg[base + j] : 0;
    s += v[j];
  }
  sh[threadIdx.x] = s;
  __syncthreads();
  for (int off = 1; off < SCAN_B; off <<= 1) {
    int t = (threadIdx.x >= off) ? sh[threadIdx.x - off] : 0;
    __syncthreads();
    sh[threadIdx.x] += t;
    __syncthreads();
  }
  if (threadIdx.x == SCAN_B - 1) blksum[blockIdx.x] = sh[SCAN_B - 1];
  int run = sh[threadIdx.x] - s;
#pragma unroll
  for (int j = 0; j < SCAN_E; ++j) {
    if (base + j < n) rowptr[base + j] = run;
    run += v[j];
  }
}

__global__ void scan2_kernel(int* __restrict__ blksum, int nb) {
  __shared__ int sh[SCAN_B];
  int v = (threadIdx.x < nb) ? blksum[threadIdx.x] : 0;
  sh[threadIdx.x] = v;
  __syncthreads();
  for (int off = 1; off < SCAN_B; off <<= 1) {
    int t = (threadIdx.x >= off) ? sh[threadIdx.x - off] : 0;
    __syncthreads();
    sh[threadIdx.x] += t;
    __syncthreads();
  }
  if (threadIdx.x < nb) blksum[threadIdx.x] = sh[threadIdx.x] - v;
}

__global__ void scan3_kernel(int* __restrict__ rowptr, int* __restrict__ cursor,
                             const int* __restrict__ blksum, int n) {
  int i = blockIdx.x * blockDim.x + threadIdx.x;
  if (i >= n) return;
  int v = rowptr[i] + blksum[i / (SCAN_B * SCAN_E)];
  rowptr[i] = v;
  cursor[i] = v;
}

__global__ void scatter_kernel(const int* __restrict__ row, const int* __restrict__ col,
                               int* __restrict__ cursor, int* __restrict__ eslot,
                               int* __restrict__ ecol, int E) {
  int gid = blockIdx.x * blockDim.x + threadIdx.x;
  if (gid >= E) return;
  int r = row[gid];
  int slot = atomicAdd(&cursor[r], 1);
  eslot[gid] = slot;
  ecol[slot] = col[gid];
}

// ---------------- Combo kernel: role-split {oe GEMM (stream)} + {row attn (gather)} --
__global__ void __launch_bounds__(256) combo_kernel(
    const unsigned short* __restrict__ feat, const float* __restrict__ Woe,
    const float* __restrict__ boe, float* __restrict__ oe, int E,
    const float* __restrict__ escores, const int* __restrict__ rowptr,
    const int* __restrict__ deg, const int* __restrict__ ecol,
    const unsigned short* __restrict__ vb, float* __restrict__ hout, int n) {
  const int nOe = (gridDim.x * 3) >> 3;  // 3/8 of blocks stream the oe GEMM
  if ((int)blockIdx.x < nOe) {
    int wid = (blockIdx.x * blockDim.x + threadIdx.x) >> 6;
    int nw = (nOe * blockDim.x) >> 6;
    gemm64_body<true, false>(feat, Woe, boe, oe, E, wid, nw, threadIdx.x);
    return;
  }
  // ---- row attention: one wave per row, 4 edges in flight ----
  const int nAttn = gridDim.x - nOe;
  int bid = blockIdx.x - nOe;
  int lane = threadIdx.x & 63;
  int gi = lane >> 4, j = lane & 15;
  for (int r = bid * 4 + (threadIdx.x >> 6); r < n; r += nAttn * 4) {
    int start = rowptr[r], dg = deg[r];
    f32x4 acc = (f32x4){0.f, 0.f, 0.f, 0.f};
    f32x4 den = (f32x4){0.f, 0.f, 0.f, 0.f};
    for (int i = gi; i < dg; i += 4) {
      int idx = start + i;
      int c = ecol[idx];
      f32x4 sv = *(const f32x4*)(escores + (size_t)idx * 8 + 4 * (j & 1));
      u16x4 vv = *(const u16x4*)(vb + (size_t)c * 64 + j * 4);
#pragma unroll
      for (int m = 0; m < 4; ++m) {
        float ex = __expf(sv[m]);
        den[m] += ex;
        acc[m] += ex * bf2f(vv[m]);
      }
    }
#pragma unroll
    for (int m = 0; m < 4; ++m) {
      acc[m] += __shfl_xor(acc[m], 16, 64);
      acc[m] += __shfl_xor(acc[m], 32, 64);
      den[m] += __shfl_xor(den[m], 16, 64);
      den[m] += __shfl_xor(den[m], 32, 64);
    }
    if (gi == 0) {
      f32x4 o;
#pragma unroll
      for (int m = 0; m < 4; ++m) o[m] = (dg > 0) ? acc[m] / den[m] : 0.f;
      *(f32x4*)(hout + (size_t)r * 64 + j * 4) = o;
    }
  }
}

extern "C" void kernel_launch(void* const* d_in, const int* in_sizes, int n_in,
                              void* d_out, int out_size, void* d_ws, size_t ws_size,
                              hipStream_t stream) {
  const float* hx  = (const float*)d_in[0];
  const float* he  = (const float*)d_in[1];
  const int*   row = (const int*)d_in[2];
  const int*   col = (const int*)d_in[3];
  const float* Wq = (const float*)d_in[4],  *bq = (const float*)d_in[5];
  const float* Wk = (const float*)d_in[6],  *bk = (const float*)d_in[7];
  const float* Wv = (const float*)d_in[8],  *bv = (const float*)d_in[9];
  const float* We = (const float*)d_in[10], *be = (const float*)d_in[11];
  const float* Woh = (const float*)d_in[12], *boh = (const float*)d_in[13];
  const float* Woe = (const float*)d_in[14], *boe = (const float*)d_in[15];

  const int n = in_sizes[0] / 64;
  const int E = in_sizes[2];

  float* out = (float*)d_out;
  float* oh = out;                   // n*64 fp32
  float* oe = out + (size_t)n * 64;  // E*64 fp32

  // ws: qb,kb,vbuf (n*64 bf16) | escores (E*8 f32, CSR order) | hout (n*64 f32)
  //   | deg,rowptr,cursor (n int) | blksum (256) | eslot (E) | ecol (E)
  //   | feat (E*64 bf16) | WeM (512 f32) | beM (8 f32)
  unsigned short* qb   = (unsigned short*)d_ws;
  unsigned short* kb   = qb + (size_t)n * 64;
  unsigned short* vbuf = kb + (size_t)n * 64;
  float* escores = (float*)(vbuf + (size_t)n * 64);
  float* hout    = escores + (size_t)E * 8;

  int* deg    = (int*)(hout + (size_t)n * 64);
  int* rowptr = deg + n;
  int* cursor = rowptr + n;
  int* blksum = cursor + n;
  int* eslot  = blksum + 256;
  int* ecol   = eslot + (size_t)E;
  unsigned short* feat = (unsigned short*)(ecol + (size_t)E);
  float* WeM = (float*)(feat + (size_t)E * 64);
  float* beM = WeM + 512;

  const int nb_scan = (n + SCAN_B * SCAN_E - 1) / (SCAN_B * SCAN_E);

  // CSR build (depends only on row/col)
  zero_kernel<<<(n + 255) / 256, 256, 0, stream>>>(deg, n);
  hist_kernel<<<(E + 255) / 256, 256, 0, stream>>>(row, deg, E);
  scan1_kernel<<<nb_scan, SCAN_B, 0, stream>>>(deg, rowptr, blksum, n);
  scan2_kernel<<<1, SCAN_B, 0, stream>>>(blksum, nb_scan);
  scan3_kernel<<<(n + 255) / 256, 256, 0, stream>>>(rowptr, cursor, blksum, n);
  scatter_kernel<<<(E + 255) / 256, 256, 0, stream>>>(row, col, cursor, eslot, ecol, E);

  qkv3_kernel<<<512, 256, 0, stream>>>(hx, Wq, bq, Wk, bk, Wv, bv, qb, kb, vbuf, n);
  wemprep_kernel<<<1, 512, 0, stream>>>(We, be, WeM, beM);

  edge_fused_kernel<<<2048, 256, 0, stream>>>(he, row, col, eslot, qb, kb, We, be,
                                              WeM, beM, feat, escores, E);

  combo_kernel<<<4096, 256, 0, stream>>>(feat, Woe, boe, oe, E,
                                         escores, rowptr, deg, ecol, vbuf, hout, n);

  gemm64_kernel<false, false><<<512, 256, 0, stream>>>(hout, Woh, boh, oh, n);
}

// Round 13
// 596.301 us; speedup vs baseline: 1.2505x; 1.2505x over previous
//
#include <hip/hip_runtime.h>

typedef __attribute__((ext_vector_type(8))) short bf16x8;
typedef __attribute__((ext_vector_type(4))) float f32x4;
typedef __attribute__((ext_vector_type(16))) unsigned char u8x16;

__device__ __forceinline__ float bf2f(unsigned short h) {
  return __uint_as_float(((unsigned)h) << 16);
}
__device__ __forceinline__ unsigned cvtpk(float a, float b) {
  unsigned r;
  asm("v_cvt_pk_bf16_f32 %0, %1, %2" : "=v"(r) : "v"(a), "v"(b));
  return r;
}
__device__ __forceinline__ unsigned short f2bf(float f) {
  return (unsigned short)(cvtpk(f, f) & 0xffffu);
}
__device__ __forceinline__ bf16x8 pack8(f32x4 x0, f32x4 x1) {
  union { bf16x8 v; unsigned u[4]; } z;
  z.u[0] = cvtpk(x0[0], x0[1]);
  z.u[1] = cvtpk(x0[2], x0[3]);
  z.u[2] = cvtpk(x1[0], x1[1]);
  z.u[3] = cvtpk(x1[2], x1[3]);
  return z.v;
}

// frag-permuted byte position for col (0..63):
// col<32: f = (col>>3)*16 + (col&7);  col>=32: f = ((col-32)>>3)*16 + 8 + ((col-32)&7)
__device__ __forceinline__ int fragpos(int nb, int n15) {
  return (((nb & 1) * 2 + (n15 >> 3)) << 4) + ((nb >> 1) << 3) + (n15 & 7);
}

// ---------------- GEMM64: out[M,64] = A[M,64] @ W[64,64] + b ----------------
template<bool IN_BF16, bool OUT_BF16>
__global__ void __launch_bounds__(256) gemm64_kernel(const void* __restrict__ Ain,
    const float* __restrict__ W, const float* __restrict__ bias,
    void* __restrict__ Out, int M) {
  const int tid = threadIdx.x;
  const int l = tid & 63;
  const int g = l >> 4;
  const int n15 = l & 15;

  bf16x8 bfrag[4][2];
  float bv[4];
#pragma unroll
  for (int nb = 0; nb < 4; ++nb) {
    bv[nb] = bias[nb * 16 + n15];
#pragma unroll
    for (int kb = 0; kb < 2; ++kb)
#pragma unroll
      for (int j = 0; j < 8; ++j)
        bfrag[nb][kb][j] = (short)f2bf(W[(kb * 32 + g * 8 + j) * 64 + nb * 16 + n15]);
  }

  int wid = (blockIdx.x * blockDim.x + tid) >> 6;
  int nw = (gridDim.x * blockDim.x) >> 6;
  int ntiles = (M + 15) >> 4;
  for (int t = wid; t < ntiles; t += nw) {
    int m0 = t << 4;
    int arow = m0 + n15;
    bf16x8 a0, a1;
    if (arow < M) {
      if constexpr (IN_BF16) {
        const unsigned short* ap = (const unsigned short*)Ain + (size_t)arow * 64 + g * 8;
        a0 = *(const bf16x8*)ap;
        a1 = *(const bf16x8*)(ap + 32);
      } else {
        const float* ap = (const float*)Ain + (size_t)arow * 64 + g * 8;
        a0 = pack8(*(const f32x4*)ap, *(const f32x4*)(ap + 4));
        a1 = pack8(*(const f32x4*)(ap + 32), *(const f32x4*)(ap + 36));
      }
    } else {
#pragma unroll
      for (int j = 0; j < 8; ++j) { a0[j] = 0; a1[j] = 0; }
    }
    f32x4 acc[4];
#pragma unroll
    for (int nb = 0; nb < 4; ++nb) {
      acc[nb] = (f32x4){bv[nb], bv[nb], bv[nb], bv[nb]};
      acc[nb] = __builtin_amdgcn_mfma_f32_16x16x32_bf16(a0, bfrag[nb][0], acc[nb], 0, 0, 0);
      acc[nb] = __builtin_amdgcn_mfma_f32_16x16x32_bf16(a1, bfrag[nb][1], acc[nb], 0, 0, 0);
    }
#pragma unroll
    for (int nb = 0; nb < 4; ++nb)
#pragma unroll
      for (int r = 0; r < 4; ++r) {
        int orow = m0 + g * 4 + r;
        if (orow < M) {
          float val = acc[nb][r];
          size_t oidx = (size_t)orow * 64 + nb * 16 + n15;
          if constexpr (OUT_BF16) ((unsigned short*)Out)[oidx] = f2bf(val);
          else                    ((float*)Out)[oidx] = val;
        }
      }
  }
}

// Fused q/k/v -> int8 rows with per-row scales. q/k in frag-permuted byte order
// (64B row = 1 line, one u8x16 per lane-group in the edge kernel); v in plain order.
__global__ void __launch_bounds__(256) qkv3_kernel(const float* __restrict__ hx,
    const float* __restrict__ Wq, const float* __restrict__ bq,
    const float* __restrict__ Wk, const float* __restrict__ bk,
    const float* __restrict__ Wv, const float* __restrict__ bv,
    signed char* __restrict__ q8, signed char* __restrict__ k8,
    signed char* __restrict__ v8,
    float* __restrict__ sq, float* __restrict__ sk, float* __restrict__ sv, int M) {
  const int tid = threadIdx.x;
  const int l = tid & 63;
  const int g = l >> 4;
  const int n15 = l & 15;
  const float* Ws[3] = {Wq, Wk, Wv};
  const float* bs[3] = {bq, bk, bv};
  signed char* outs[3] = {q8, k8, v8};
  float* scl[3] = {sq, sk, sv};

  bf16x8 bfrag[3][4][2];
  float bvv[3][4];
#pragma unroll
  for (int w = 0; w < 3; ++w)
#pragma unroll
    for (int nb = 0; nb < 4; ++nb) {
      bvv[w][nb] = bs[w][nb * 16 + n15];
#pragma unroll
      for (int kb = 0; kb < 2; ++kb)
#pragma unroll
        for (int j = 0; j < 8; ++j)
          bfrag[w][nb][kb][j] = (short)f2bf(Ws[w][(kb * 32 + g * 8 + j) * 64 + nb * 16 + n15]);
    }

  int wid = (blockIdx.x * blockDim.x + tid) >> 6;
  int nw = (gridDim.x * blockDim.x) >> 6;
  int ntiles = (M + 15) >> 4;
  for (int t = wid; t < ntiles; t += nw) {
    int m0 = t << 4;
    int arow = m0 + n15;
    bf16x8 a0, a1;
    if (arow < M) {
      const float* ap = hx + (size_t)arow * 64 + g * 8;
      a0 = pack8(*(const f32x4*)ap, *(const f32x4*)(ap + 4));
      a1 = pack8(*(const f32x4*)(ap + 32), *(const f32x4*)(ap + 36));
    } else {
#pragma unroll
      for (int j = 0; j < 8; ++j) { a0[j] = 0; a1[j] = 0; }
    }
#pragma unroll
    for (int w = 0; w < 3; ++w) {
      f32x4 acc[4];
#pragma unroll
      for (int nb = 0; nb < 4; ++nb) {
        acc[nb] = (f32x4){bvv[w][nb], bvv[w][nb], bvv[w][nb], bvv[w][nb]};
        acc[nb] = __builtin_amdgcn_mfma_f32_16x16x32_bf16(a0, bfrag[w][nb][0], acc[nb], 0, 0, 0);
        acc[nb] = __builtin_amdgcn_mfma_f32_16x16x32_bf16(a1, bfrag[w][nb][1], acc[nb], 0, 0, 0);
      }
      // per-row absmax (rows g*4+r spread over the 16 n15 lanes of group g)
#pragma unroll
      for (int r = 0; r < 4; ++r) {
        float am = fmaxf(fmaxf(fabsf(acc[0][r]), fabsf(acc[1][r])),
                         fmaxf(fabsf(acc[2][r]), fabsf(acc[3][r])));
        am = fmaxf(am, __shfl_xor(am, 1, 64));
        am = fmaxf(am, __shfl_xor(am, 2, 64));
        am = fmaxf(am, __shfl_xor(am, 4, 64));
        am = fmaxf(am, __shfl_xor(am, 8, 64));
        am = fmaxf(am, 1e-10f);
        float inv = 127.0f / am;
        int orow = m0 + g * 4 + r;
        if (orow < M) {
          if (n15 == 0) scl[w][orow] = am / 127.0f;
#pragma unroll
          for (int nb = 0; nb < 4; ++nb) {
            int qi = __float2int_rn(acc[nb][r] * inv);
            int pos = (w == 2) ? (nb * 16 + n15) : fragpos(nb, n15);
            outs[w][(size_t)orow * 64 + pos] = (signed char)qi;
          }
        }
      }
    }
  }
}

// WeM[d][h] = sum_m We[d][m*8+h] * (1/sqrt(8)); beM[h] likewise from be.
__global__ void wemprep_kernel(const float* __restrict__ We, const float* __restrict__ be,
                               float* __restrict__ WeM, float* __restrict__ beM) {
  int tid = threadIdx.x;
  if (tid < 512) {
    int d = tid >> 3, h = tid & 7;
    float s = 0.f;
#pragma unroll
    for (int m = 0; m < 8; ++m) s += We[d * 64 + m * 8 + h];
    WeM[d * 8 + h] = s * 0.35355339059327373f;
  }
  if (tid < 8) {
    float s = 0.f;
#pragma unroll
    for (int m = 0; m < 8; ++m) s += be[tid + m * 8];
    beM[tid] = s * 0.35355339059327373f;
  }
}

// ---------------- Fused edge pipeline v5: all-MFMA + int8 gathers -------------------
// gate = he@WeM+beM (C-layout col=head); p_int = (q8⊙k8)@Mask (exact int products);
// s = p*gate*(sq*sk); escores[slot]=s; oe = (s*elin)@Woe+boe via per-wave LDS transpose.
__global__ void __launch_bounds__(256) edge_fused_kernel(
    const float* __restrict__ he,
    const int* __restrict__ rowi, const int* __restrict__ coli,
    const int* __restrict__ eslot,
    const signed char* __restrict__ q8, const signed char* __restrict__ k8,
    const float* __restrict__ sq, const float* __restrict__ sk,
    const float* __restrict__ We, const float* __restrict__ be,
    const float* __restrict__ Woe, const float* __restrict__ boe,
    const float* __restrict__ WeM, const float* __restrict__ beM,
    float* __restrict__ oe, float* __restrict__ escores, int E) {
  const int tid = threadIdx.x;
  const int wv = tid >> 6;
  const int l = tid & 63;
  const int g = l >> 4;
  const int n15 = l & 15;

  __shared__ unsigned short feat_lds[4][16 * 72];

  bf16x8 bfE[4][2], bfO[4][2];
  float beV[4], boV[4];
#pragma unroll
  for (int nb = 0; nb < 4; ++nb) {
    beV[nb] = be[nb * 16 + n15];
    boV[nb] = boe[nb * 16 + n15];
#pragma unroll
    for (int kb = 0; kb < 2; ++kb)
#pragma unroll
      for (int j = 0; j < 8; ++j) {
        bfE[nb][kb][j] = (short)f2bf(We[(kb * 32 + g * 8 + j) * 64 + nb * 16 + n15]);
        bfO[nb][kb][j] = (short)f2bf(Woe[(kb * 32 + g * 8 + j) * 64 + nb * 16 + n15]);
      }
  }
  bf16x8 gB0, gB1, mB;
  const bool hv = (n15 < 8);
#pragma unroll
  for (int j = 0; j < 8; ++j) {
    gB0[j] = hv ? (short)f2bf(WeM[(g * 8 + j) * 8 + n15]) : (short)0;
    gB1[j] = hv ? (short)f2bf(WeM[(32 + g * 8 + j) * 8 + n15]) : (short)0;
    mB[j]  = (hv && j == n15) ? (short)0x3F80 : (short)0;  // bf16 1.0
  }
  const float beMv = hv ? beM[n15] : 0.f;

  const int ntiles = (E + 15) >> 4;
  int wid = (blockIdx.x * blockDim.x + tid) >> 6;
  int nw = (gridDim.x * blockDim.x) >> 6;
  for (int t = wid; t < ntiles; t += nw) {
    const int m0 = t << 4;
    const int es = min(m0 + n15, E - 1);  // clamp -> dup rows; stores guarded
    const int rq = rowi[es], rc = coli[es], sl = eslot[es];

    // int8 gathers: one 16B load each (64B row = 1 line) + scales
    u8x16 qv = *(const u8x16*)(q8 + (size_t)rq * 64 + g * 16);
    u8x16 kv = *(const u8x16*)(k8 + (size_t)rc * 64 + g * 16);
    const float sqk = sq[rq] * sk[rc];

    // he A-frags (contiguous stream)
    const float* ap = he + (size_t)es * 64 + g * 8;
    bf16x8 a0 = pack8(*(const f32x4*)ap, *(const f32x4*)(ap + 4));
    bf16x8 a1 = pack8(*(const f32x4*)(ap + 32), *(const f32x4*)(ap + 36));

    // elin + gate
    f32x4 acc[4];
#pragma unroll
    for (int nb = 0; nb < 4; ++nb) {
      acc[nb] = (f32x4){beV[nb], beV[nb], beV[nb], beV[nb]};
      acc[nb] = __builtin_amdgcn_mfma_f32_16x16x32_bf16(a0, bfE[nb][0], acc[nb], 0, 0, 0);
      acc[nb] = __builtin_amdgcn_mfma_f32_16x16x32_bf16(a1, bfE[nb][1], acc[nb], 0, 0, 0);
    }
    f32x4 gate = (f32x4){beMv, beMv, beMv, beMv};
    gate = __builtin_amdgcn_mfma_f32_16x16x32_bf16(a0, gB0, gate, 0, 0, 0);
    gate = __builtin_amdgcn_mfma_f32_16x16x32_bf16(a1, gB1, gate, 0, 0, 0);

    // exact int products -> bf16 A-frags -> masked MFMA = per-head unscaled dots
    f32x4 p0a, p0b, p1a, p1b;
#pragma unroll
    for (int j = 0; j < 4; ++j) {
      p0a[j] = (float)((int)(signed char)qv[j]      * (int)(signed char)kv[j]);
      p0b[j] = (float)((int)(signed char)qv[4 + j]  * (int)(signed char)kv[4 + j]);
      p1a[j] = (float)((int)(signed char)qv[8 + j]  * (int)(signed char)kv[8 + j]);
      p1b[j] = (float)((int)(signed char)qv[12 + j] * (int)(signed char)kv[12 + j]);
    }
    bf16x8 pa0 = pack8(p0a, p0b), pa1 = pack8(p1a, p1b);
    f32x4 p = (f32x4){0.f, 0.f, 0.f, 0.f};
    p = __builtin_amdgcn_mfma_f32_16x16x32_bf16(pa0, mB, p, 0, 0, 0);
    p = __builtin_amdgcn_mfma_f32_16x16x32_bf16(pa1, mB, p, 0, 0, 0);

    // s = p * gate * sqk(edge)   (valid at n15<8)
    float s_[4];
#pragma unroll
    for (int r = 0; r < 4; ++r)
      s_[r] = p[r] * gate[r] * __shfl(sqk, g * 4 + r, 64);
#pragma unroll
    for (int r = 0; r < 4; ++r) {
      int slot = __shfl(sl, g * 4 + r, 64);
      if (hv && m0 + g * 4 + r < E) escores[(size_t)slot * 8 + n15] = s_[r];
    }
    // spread s to upper half-lanes (head = n15&7)
#pragma unroll
    for (int r = 0; r < 4; ++r) {
      float o = __shfl_xor(s_[r], 8, 64);
      if (!hv) s_[r] = o;
    }
    // feat = s*elin -> LDS transpose (wave-local, in-order DS; validated fence-free)
#pragma unroll
    for (int nb = 0; nb < 4; ++nb)
#pragma unroll
      for (int r = 0; r < 4; ++r)
        feat_lds[wv][(g * 4 + r) * 72 + nb * 16 + n15] = f2bf(s_[r] * acc[nb][r]);
    const unsigned short* fpt = &feat_lds[wv][n15 * 72 + g * 8];
    a0 = *(const bf16x8*)fpt;
    a1 = *(const bf16x8*)(fpt + 32);
#pragma unroll
    for (int nb = 0; nb < 4; ++nb) {
      f32x4 c2 = (f32x4){boV[nb], boV[nb], boV[nb], boV[nb]};
      c2 = __builtin_amdgcn_mfma_f32_16x16x32_bf16(a0, bfO[nb][0], c2, 0, 0, 0);
      c2 = __builtin_amdgcn_mfma_f32_16x16x32_bf16(a1, bfO[nb][1], c2, 0, 0, 0);
#pragma unroll
      for (int r = 0; r < 4; ++r) {
        int orow = m0 + g * 4 + r;
        if (orow < E) oe[(size_t)orow * 64 + nb * 16 + n15] = c2[r];
      }
    }
  }
}

// ---------------- CSR build ----------------
__global__ void zero_kernel(int* __restrict__ p, int n) {
  int i = blockIdx.x * blockDim.x + threadIdx.x;
  if (i < n) p[i] = 0;
}

__global__ void hist_kernel(const int* __restrict__ row, int* __restrict__ deg, int E) {
  int gid = blockIdx.x * blockDim.x + threadIdx.x;
  if (gid < E) atomicAdd(&deg[row[gid]], 1);
}

#define SCAN_B 256
#define SCAN_E 8
__global__ void scan1_kernel(const int* __restrict__ deg, int* __restrict__ rowptr,
                             int* __restrict__ blksum, int n) {
  __shared__ int sh[SCAN_B];
  int base = blockIdx.x * (SCAN_B * SCAN_E) + threadIdx.x * SCAN_E;
  int v[SCAN_E];
  int s = 0;
#pragma unroll
  for (int j = 0; j < SCAN_E; ++j) {
    v[j] = (base + j < n) ? deg[base + j] : 0;
    s += v[j];
  }
  sh[threadIdx.x] = s;
  __syncthreads();
  for (int off = 1; off < SCAN_B; off <<= 1) {
    int t = (threadIdx.x >= off) ? sh[threadIdx.x - off] : 0;
    __syncthreads();
    sh[threadIdx.x] += t;
    __syncthreads();
  }
  if (threadIdx.x == SCAN_B - 1) blksum[blockIdx.x] = sh[SCAN_B - 1];
  int run = sh[threadIdx.x] - s;
#pragma unroll
  for (int j = 0; j < SCAN_E; ++j) {
    if (base + j < n) rowptr[base + j] = run;
    run += v[j];
  }
}

__global__ void scan2_kernel(int* __restrict__ blksum, int nb) {
  __shared__ int sh[SCAN_B];
  int v = (threadIdx.x < nb) ? blksum[threadIdx.x] : 0;
  sh[threadIdx.x] = v;
  __syncthreads();
  for (int off = 1; off < SCAN_B; off <<= 1) {
    int t = (threadIdx.x >= off) ? sh[threadIdx.x - off] : 0;
    __syncthreads();
    sh[threadIdx.x] += t;
    __syncthreads();
  }
  if (threadIdx.x < nb) blksum[threadIdx.x] = sh[threadIdx.x] - v;
}

__global__ void scan3_kernel(int* __restrict__ rowptr, int* __restrict__ cursor,
                             const int* __restrict__ blksum, int n) {
  int i = blockIdx.x * blockDim.x + threadIdx.x;
  if (i >= n) return;
  int v = rowptr[i] + blksum[i / (SCAN_B * SCAN_E)];
  rowptr[i] = v;
  cursor[i] = v;
}

__global__ void scatter_kernel(const int* __restrict__ row, const int* __restrict__ col,
                               int* __restrict__ cursor, int* __restrict__ eslot,
                               int* __restrict__ ecol, int E) {
  int gid = blockIdx.x * blockDim.x + threadIdx.x;
  if (gid >= E) return;
  int r = row[gid];
  int slot = atomicAdd(&cursor[r], 1);
  eslot[gid] = slot;
  ecol[slot] = col[gid];
}

// One wave per row, 4 edges in flight; v in int8 (64B row + 4B scale per gather).
__global__ void __launch_bounds__(256) row_attn_kernel(const float* __restrict__ escores,
    const int* __restrict__ rowptr, const int* __restrict__ deg,
    const int* __restrict__ ecol,
    const signed char* __restrict__ v8, const float* __restrict__ sv,
    float* __restrict__ hout, int n) {
  int gid = blockIdx.x * blockDim.x + threadIdx.x;
  int r = gid >> 6, lane = threadIdx.x & 63;
  if (r >= n) return;
  int gi = lane >> 4, j = lane & 15;
  int start = rowptr[r], dg = deg[r];

  f32x4 acc = (f32x4){0.f, 0.f, 0.f, 0.f};
  f32x4 den = (f32x4){0.f, 0.f, 0.f, 0.f};
  for (int i = gi; i < dg; i += 4) {
    int idx = start + i;
    int c = ecol[idx];
    f32x4 svec = *(const f32x4*)(escores + (size_t)idx * 8 + 4 * (j & 1));
    unsigned vvu = *(const unsigned*)(v8 + (size_t)c * 64 + j * 4);
    float scv = sv[c];
#pragma unroll
    for (int m = 0; m < 4; ++m) {
      float ex = __expf(svec[m]);
      float vm = (float)((signed char)((vvu >> (8 * m)) & 0xff));
      den[m] += ex;
      acc[m] += ex * scv * vm;
    }
  }
#pragma unroll
  for (int m = 0; m < 4; ++m) {
    acc[m] += __shfl_xor(acc[m], 16, 64);
    acc[m] += __shfl_xor(acc[m], 32, 64);
    den[m] += __shfl_xor(den[m], 16, 64);
    den[m] += __shfl_xor(den[m], 32, 64);
  }
  if (gi == 0) {
    f32x4 o;
#pragma unroll
    for (int m = 0; m < 4; ++m) o[m] = (dg > 0) ? acc[m] / den[m] : 0.f;
    *(f32x4*)(hout + (size_t)r * 64 + j * 4) = o;
  }
}

extern "C" void kernel_launch(void* const* d_in, const int* in_sizes, int n_in,
                              void* d_out, int out_size, void* d_ws, size_t ws_size,
                              hipStream_t stream) {
  const float* hx  = (const float*)d_in[0];
  const float* he  = (const float*)d_in[1];
  const int*   row = (const int*)d_in[2];
  const int*   col = (const int*)d_in[3];
  const float* Wq = (const float*)d_in[4],  *bq = (const float*)d_in[5];
  const float* Wk = (const float*)d_in[6],  *bk = (const float*)d_in[7];
  const float* Wv = (const float*)d_in[8],  *bv = (const float*)d_in[9];
  const float* We = (const float*)d_in[10], *be = (const float*)d_in[11];
  const float* Woh = (const float*)d_in[12], *boh = (const float*)d_in[13];
  const float* Woe = (const float*)d_in[14], *boe = (const float*)d_in[15];

  const int n = in_sizes[0] / 64;
  const int E = in_sizes[2];

  float* out = (float*)d_out;
  float* oh = out;                   // n*64 fp32
  float* oe = out + (size_t)n * 64;  // E*64 fp32

  // ws: q8,k8,v8 (n*64 B) | sq,sk,sv (n f32) | escores (E*8 f32) | hout (n*64 f32)
  //   | deg,rowptr,cursor (n) | blksum (256) | eslot (E) | ecol (E) | WeM,beM
  signed char* q8 = (signed char*)d_ws;
  signed char* k8 = q8 + (size_t)n * 64;
  signed char* v8 = k8 + (size_t)n * 64;
  float* sq = (float*)(v8 + (size_t)n * 64);
  float* sk = sq + n;
  float* sv = sk + n;
  float* escores = sv + n;
  float* hout    = escores + (size_t)E * 8;

  int* deg    = (int*)(hout + (size_t)n * 64);
  int* rowptr = deg + n;
  int* cursor = rowptr + n;
  int* blksum = cursor + n;
  int* eslot  = blksum + 256;
  int* ecol   = eslot + (size_t)E;
  float* WeM  = (float*)(ecol + (size_t)E);
  float* beM  = WeM + 512;

  const int nb_scan = (n + SCAN_B * SCAN_E - 1) / (SCAN_B * SCAN_E);

  // CSR build (depends only on row/col)
  zero_kernel<<<(n + 255) / 256, 256, 0, stream>>>(deg, n);
  hist_kernel<<<(E + 255) / 256, 256, 0, stream>>>(row, deg, E);
  scan1_kernel<<<nb_scan, SCAN_B, 0, stream>>>(deg, rowptr, blksum, n);
  scan2_kernel<<<1, SCAN_B, 0, stream>>>(blksum, nb_scan);
  scan3_kernel<<<(n + 255) / 256, 256, 0, stream>>>(rowptr, cursor, blksum, n);
  scatter_kernel<<<(E + 255) / 256, 256, 0, stream>>>(row, col, cursor, eslot, ecol, E);

  qkv3_kernel<<<512, 256, 0, stream>>>(hx, Wq, bq, Wk, bk, Wv, bv,
                                       q8, k8, v8, sq, sk, sv, n);
  wemprep_kernel<<<1, 512, 0, stream>>>(We, be, WeM, beM);

  edge_fused_kernel<<<2048, 256, 0, stream>>>(he, row, col, eslot, q8, k8, sq, sk,
                                              We, be, Woe, boe, WeM, beM,
                                              oe, escores, E);

  row_attn_kernel<<<(n + 3) / 4, 256, 0, stream>>>(escores, rowptr, deg, ecol,
                                                   v8, sv, hout, n);
  gemm64_kernel<false, false><<<512, 256, 0, stream>>>(hout, Woh, boh, oh, n);
}

// Round 14
// 517.256 us; speedup vs baseline: 1.4416x; 1.1528x over previous
//
#include <hip/hip_runtime.h>

typedef __attribute__((ext_vector_type(8))) short bf16x8;
typedef __attribute__((ext_vector_type(4))) float f32x4;
typedef __attribute__((ext_vector_type(4))) unsigned short u16x4;

__device__ __forceinline__ float bf2f(unsigned short h) {
  return __uint_as_float(((unsigned)h) << 16);
}
__device__ __forceinline__ unsigned cvtpk(float a, float b) {
  unsigned r;
  asm("v_cvt_pk_bf16_f32 %0, %1, %2" : "=v"(r) : "v"(a), "v"(b));
  return r;
}
__device__ __forceinline__ unsigned short f2bf(float f) {
  return (unsigned short)(cvtpk(f, f) & 0xffffu);
}
__device__ __forceinline__ bf16x8 pack8(f32x4 x0, f32x4 x1) {
  union { bf16x8 v; unsigned u[4]; } z;
  z.u[0] = cvtpk(x0[0], x0[1]);
  z.u[1] = cvtpk(x0[2], x0[3]);
  z.u[2] = cvtpk(x1[0], x1[1]);
  z.u[3] = cvtpk(x1[2], x1[3]);
  return z.v;
}

// ---------------- GEMM64: out[M,64] = A[M,64] @ W[64,64] + b ----------------
template<bool IN_BF16, bool OUT_BF16>
__global__ void __launch_bounds__(256) gemm64_kernel(const void* __restrict__ Ain,
    const float* __restrict__ W, const float* __restrict__ bias,
    void* __restrict__ Out, int M) {
  const int tid = threadIdx.x;
  const int l = tid & 63;
  const int g = l >> 4;
  const int n15 = l & 15;

  bf16x8 bfrag[4][2];
  float bv[4];
#pragma unroll
  for (int nb = 0; nb < 4; ++nb) {
    bv[nb] = bias[nb * 16 + n15];
#pragma unroll
    for (int kb = 0; kb < 2; ++kb)
#pragma unroll
      for (int j = 0; j < 8; ++j)
        bfrag[nb][kb][j] = (short)f2bf(W[(kb * 32 + g * 8 + j) * 64 + nb * 16 + n15]);
  }

  int wid = (blockIdx.x * blockDim.x + tid) >> 6;
  int nw = (gridDim.x * blockDim.x) >> 6;
  int ntiles = (M + 15) >> 4;
  for (int t = wid; t < ntiles; t += nw) {
    int m0 = t << 4;
    int arow = m0 + n15;
    bf16x8 a0, a1;
    if (arow < M) {
      if constexpr (IN_BF16) {
        const unsigned short* ap = (const unsigned short*)Ain + (size_t)arow * 64 + g * 8;
        a0 = *(const bf16x8*)ap;
        a1 = *(const bf16x8*)(ap + 32);
      } else {
        const float* ap = (const float*)Ain + (size_t)arow * 64 + g * 8;
        a0 = pack8(*(const f32x4*)ap, *(const f32x4*)(ap + 4));
        a1 = pack8(*(const f32x4*)(ap + 32), *(const f32x4*)(ap + 36));
      }
    } else {
#pragma unroll
      for (int j = 0; j < 8; ++j) { a0[j] = 0; a1[j] = 0; }
    }
    f32x4 acc[4];
#pragma unroll
    for (int nb = 0; nb < 4; ++nb) {
      acc[nb] = (f32x4){bv[nb], bv[nb], bv[nb], bv[nb]};
      acc[nb] = __builtin_amdgcn_mfma_f32_16x16x32_bf16(a0, bfrag[nb][0], acc[nb], 0, 0, 0);
      acc[nb] = __builtin_amdgcn_mfma_f32_16x16x32_bf16(a1, bfrag[nb][1], acc[nb], 0, 0, 0);
    }
#pragma unroll
    for (int nb = 0; nb < 4; ++nb)
#pragma unroll
      for (int r = 0; r < 4; ++r) {
        int orow = m0 + g * 4 + r;
        if (orow < M) {
          float val = acc[nb][r];
          size_t oidx = (size_t)orow * 64 + nb * 16 + n15;
          if constexpr (OUT_BF16) ((unsigned short*)Out)[oidx] = f2bf(val);
          else                    ((float*)Out)[oidx] = val;
        }
      }
  }
}

// Fused q/k/v: 3 weight sets resident, hx read once, bf16 outputs.
__global__ void __launch_bounds__(256) qkv3_kernel(const float* __restrict__ hx,
    const float* __restrict__ Wq, const float* __restrict__ bq,
    const float* __restrict__ Wk, const float* __restrict__ bk,
    const float* __restrict__ Wv, const float* __restrict__ bv,
    unsigned short* __restrict__ q, unsigned short* __restrict__ k,
    unsigned short* __restrict__ v, int M) {
  const int tid = threadIdx.x;
  const int l = tid & 63;
  const int g = l >> 4;
  const int n15 = l & 15;
  const float* Ws[3] = {Wq, Wk, Wv};
  const float* bs[3] = {bq, bk, bv};
  unsigned short* outs[3] = {q, k, v};

  bf16x8 bfrag[3][4][2];
  float bvv[3][4];
#pragma unroll
  for (int w = 0; w < 3; ++w)
#pragma unroll
    for (int nb = 0; nb < 4; ++nb) {
      bvv[w][nb] = bs[w][nb * 16 + n15];
#pragma unroll
      for (int kb = 0; kb < 2; ++kb)
#pragma unroll
        for (int j = 0; j < 8; ++j)
          bfrag[w][nb][kb][j] = (short)f2bf(Ws[w][(kb * 32 + g * 8 + j) * 64 + nb * 16 + n15]);
    }

  int wid = (blockIdx.x * blockDim.x + tid) >> 6;
  int nw = (gridDim.x * blockDim.x) >> 6;
  int ntiles = (M + 15) >> 4;
  for (int t = wid; t < ntiles; t += nw) {
    int m0 = t << 4;
    int arow = m0 + n15;
    bf16x8 a0, a1;
    if (arow < M) {
      const float* ap = hx + (size_t)arow * 64 + g * 8;
      a0 = pack8(*(const f32x4*)ap, *(const f32x4*)(ap + 4));
      a1 = pack8(*(const f32x4*)(ap + 32), *(const f32x4*)(ap + 36));
    } else {
#pragma unroll
      for (int j = 0; j < 8; ++j) { a0[j] = 0; a1[j] = 0; }
    }
#pragma unroll
    for (int w = 0; w < 3; ++w) {
      f32x4 acc[4];
#pragma unroll
      for (int nb = 0; nb < 4; ++nb) {
        acc[nb] = (f32x4){bvv[w][nb], bvv[w][nb], bvv[w][nb], bvv[w][nb]};
        acc[nb] = __builtin_amdgcn_mfma_f32_16x16x32_bf16(a0, bfrag[w][nb][0], acc[nb], 0, 0, 0);
        acc[nb] = __builtin_amdgcn_mfma_f32_16x16x32_bf16(a1, bfrag[w][nb][1], acc[nb], 0, 0, 0);
      }
#pragma unroll
      for (int nb = 0; nb < 4; ++nb)
#pragma unroll
        for (int r = 0; r < 4; ++r) {
          int orow = m0 + g * 4 + r;
          if (orow < M)
            outs[w][(size_t)orow * 64 + nb * 16 + n15] = f2bf(acc[nb][r]);
        }
    }
  }
}

// WeM[d][h] = sum_m We[d][m*8+h] * (1/sqrt(8)); beM[h] likewise from be.
__global__ void wemprep_kernel(const float* __restrict__ We, const float* __restrict__ be,
                               float* __restrict__ WeM, float* __restrict__ beM) {
  int tid = threadIdx.x;
  if (tid < 512) {
    int d = tid >> 3, h = tid & 7;
    float s = 0.f;
#pragma unroll
    for (int m = 0; m < 8; ++m) s += We[d * 64 + m * 8 + h];
    WeM[d * 8 + h] = s * 0.35355339059327373f;
  }
  if (tid < 8) {
    float s = 0.f;
#pragma unroll
    for (int m = 0; m < 8; ++m) s += be[tid + m * 8];
    beM[tid] = s * 0.35355339059327373f;
  }
}

// ---------------- Fused edge pipeline v6: all-MFMA + 1-iter-ahead gather pipeline ---
// Pipeline per wave: hold q/k regs for tile t; ISSUE t+1's q/k gathers and t+2's
// index loads BEFORE t's compute (~1500cy of MFMA) -> gather latency fully hidden.
__global__ void __launch_bounds__(256) edge_fused_kernel(
    const float* __restrict__ he,
    const int* __restrict__ rowi, const int* __restrict__ coli,
    const int* __restrict__ eslot,
    const unsigned short* __restrict__ qb, const unsigned short* __restrict__ kbuf,
    const float* __restrict__ We, const float* __restrict__ be,
    const float* __restrict__ Woe, const float* __restrict__ boe,
    const float* __restrict__ WeM, const float* __restrict__ beM,
    float* __restrict__ oe, float* __restrict__ escores, int E) {
  const int tid = threadIdx.x;
  const int wv = tid >> 6;
  const int l = tid & 63;
  const int g = l >> 4;
  const int n15 = l & 15;

  __shared__ unsigned short feat_lds[4][16 * 72];

  bf16x8 bfE[4][2], bfO[4][2];
  float beV[4], boV[4];
#pragma unroll
  for (int nb = 0; nb < 4; ++nb) {
    beV[nb] = be[nb * 16 + n15];
    boV[nb] = boe[nb * 16 + n15];
#pragma unroll
    for (int kb = 0; kb < 2; ++kb)
#pragma unroll
      for (int j = 0; j < 8; ++j) {
        bfE[nb][kb][j] = (short)f2bf(We[(kb * 32 + g * 8 + j) * 64 + nb * 16 + n15]);
        bfO[nb][kb][j] = (short)f2bf(Woe[(kb * 32 + g * 8 + j) * 64 + nb * 16 + n15]);
      }
  }
  bf16x8 gB0, gB1, mB;
  const bool hv = (n15 < 8);
#pragma unroll
  for (int j = 0; j < 8; ++j) {
    gB0[j] = hv ? (short)f2bf(WeM[(g * 8 + j) * 8 + n15]) : (short)0;
    gB1[j] = hv ? (short)f2bf(WeM[(32 + g * 8 + j) * 8 + n15]) : (short)0;
    mB[j]  = (hv && j == n15) ? (short)0x3F80 : (short)0;  // bf16 1.0
  }
  const float beMv = hv ? beM[n15] : 0.f;

  const int ntiles = (E + 15) >> 4;
  int wid = (blockIdx.x * blockDim.x + tid) >> 6;
  int nw = (gridDim.x * blockDim.x) >> 6;
  if (wid >= ntiles) return;

  // ---- pipeline prologue ----
  int t0 = wid;
  int sl0;
  bf16x8 qv0, qv1, kv0, kv1;
  {
    int es = min((t0 << 4) + n15, E - 1);
    int rq = rowi[es], rc = coli[es];
    sl0 = eslot[es];
    const unsigned short* qp = qb + (size_t)rq * 64 + g * 8;
    const unsigned short* kp = kbuf + (size_t)rc * 64 + g * 8;
    qv0 = *(const bf16x8*)qp; qv1 = *(const bf16x8*)(qp + 32);
    kv0 = *(const bf16x8*)kp; kv1 = *(const bf16x8*)(kp + 32);
  }
  int t1 = t0 + nw;
  bool more = t1 < ntiles;
  int rq1 = 0, rc1 = 0, sl1 = 0;
  if (more) {
    int es = min((t1 << 4) + n15, E - 1);
    rq1 = rowi[es]; rc1 = coli[es]; sl1 = eslot[es];
  }

  for (;;) {
    // 1. issue NEXT tile's q/k gathers (latency hides under this tile's compute)
    bf16x8 nqv0 = qv0, nqv1 = qv1, nkv0 = kv0, nkv1 = kv1;
    if (more) {
      const unsigned short* qp = qb + (size_t)rq1 * 64 + g * 8;
      const unsigned short* kp = kbuf + (size_t)rc1 * 64 + g * 8;
      nqv0 = *(const bf16x8*)qp; nqv1 = *(const bf16x8*)(qp + 32);
      nkv0 = *(const bf16x8*)kp; nkv1 = *(const bf16x8*)(kp + 32);
    }
    // 2. issue t+2's index loads
    int t2 = t1 + nw;
    bool more2 = more && (t2 < ntiles);
    int rq2 = rq1, rc2 = rc1, sl2 = sl1;
    if (more2) {
      int es = min((t2 << 4) + n15, E - 1);
      rq2 = rowi[es]; rc2 = coli[es]; sl2 = eslot[es];
    }

    // 3. ---- compute tile t0 (q/k already in regs) ----
    const int m0 = t0 << 4;
    const int es0 = min(m0 + n15, E - 1);
    const float* ap = he + (size_t)es0 * 64 + g * 8;
    bf16x8 a0 = pack8(*(const f32x4*)ap, *(const f32x4*)(ap + 4));
    bf16x8 a1 = pack8(*(const f32x4*)(ap + 32), *(const f32x4*)(ap + 36));

    f32x4 acc[4];
#pragma unroll
    for (int nb = 0; nb < 4; ++nb) {
      acc[nb] = (f32x4){beV[nb], beV[nb], beV[nb], beV[nb]};
      acc[nb] = __builtin_amdgcn_mfma_f32_16x16x32_bf16(a0, bfE[nb][0], acc[nb], 0, 0, 0);
      acc[nb] = __builtin_amdgcn_mfma_f32_16x16x32_bf16(a1, bfE[nb][1], acc[nb], 0, 0, 0);
    }
    f32x4 gate = (f32x4){beMv, beMv, beMv, beMv};
    gate = __builtin_amdgcn_mfma_f32_16x16x32_bf16(a0, gB0, gate, 0, 0, 0);
    gate = __builtin_amdgcn_mfma_f32_16x16x32_bf16(a1, gB1, gate, 0, 0, 0);

    // qk elementwise products -> bf16 A-frags -> masked MFMA = per-head dots
    f32x4 p0a, p0b, p1a, p1b;
#pragma unroll
    for (int j = 0; j < 4; ++j) {
      p0a[j] = bf2f((unsigned short)qv0[j]) * bf2f((unsigned short)kv0[j]);
      p0b[j] = bf2f((unsigned short)qv0[4 + j]) * bf2f((unsigned short)kv0[4 + j]);
      p1a[j] = bf2f((unsigned short)qv1[j]) * bf2f((unsigned short)kv1[j]);
      p1b[j] = bf2f((unsigned short)qv1[4 + j]) * bf2f((unsigned short)kv1[4 + j]);
    }
    bf16x8 pa0 = pack8(p0a, p0b), pa1 = pack8(p1a, p1b);
    f32x4 p = (f32x4){0.f, 0.f, 0.f, 0.f};
    p = __builtin_amdgcn_mfma_f32_16x16x32_bf16(pa0, mB, p, 0, 0, 0);
    p = __builtin_amdgcn_mfma_f32_16x16x32_bf16(pa1, mB, p, 0, 0, 0);

    float s_[4];
#pragma unroll
    for (int r = 0; r < 4; ++r) s_[r] = p[r] * gate[r];
#pragma unroll
    for (int r = 0; r < 4; ++r) {
      int slot = __shfl(sl0, g * 4 + r, 64);
      if (hv && m0 + g * 4 + r < E) escores[(size_t)slot * 8 + n15] = s_[r];
    }
#pragma unroll
    for (int r = 0; r < 4; ++r) {
      float o = __shfl_xor(s_[r], 8, 64);
      if (!hv) s_[r] = o;
    }
    // feat = s*elin -> LDS transpose (wave-local, in-order DS; fence-free validated)
#pragma unroll
    for (int nb = 0; nb < 4; ++nb)
#pragma unroll
      for (int r = 0; r < 4; ++r)
        feat_lds[wv][(g * 4 + r) * 72 + nb * 16 + n15] = f2bf(s_[r] * acc[nb][r]);
    const unsigned short* fpt = &feat_lds[wv][n15 * 72 + g * 8];
    a0 = *(const bf16x8*)fpt;
    a1 = *(const bf16x8*)(fpt + 32);
#pragma unroll
    for (int nb = 0; nb < 4; ++nb) {
      f32x4 c2 = (f32x4){boV[nb], boV[nb], boV[nb], boV[nb]};
      c2 = __builtin_amdgcn_mfma_f32_16x16x32_bf16(a0, bfO[nb][0], c2, 0, 0, 0);
      c2 = __builtin_amdgcn_mfma_f32_16x16x32_bf16(a1, bfO[nb][1], c2, 0, 0, 0);
#pragma unroll
      for (int r = 0; r < 4; ++r) {
        int orow = m0 + g * 4 + r;
        if (orow < E) oe[(size_t)orow * 64 + nb * 16 + n15] = c2[r];
      }
    }

    // 4. rotate pipeline
    if (!more) break;
    t0 = t1; sl0 = sl1;
    qv0 = nqv0; qv1 = nqv1; kv0 = nkv0; kv1 = nkv1;
    t1 = t2; rq1 = rq2; rc1 = rc2; sl1 = sl2;
    more = more2;
  }
}

// ---------------- CSR build ----------------
__global__ void zero_kernel(int* __restrict__ p, int n) {
  int i = blockIdx.x * blockDim.x + threadIdx.x;
  if (i < n) p[i] = 0;
}

__global__ void hist_kernel(const int* __restrict__ row, int* __restrict__ deg, int E) {
  int gid = blockIdx.x * blockDim.x + threadIdx.x;
  if (gid < E) atomicAdd(&deg[row[gid]], 1);
}

#define SCAN_B 256
#define SCAN_E 8
__global__ void scan1_kernel(const int* __restrict__ deg, int* __restrict__ rowptr,
                             int* __restrict__ blksum, int n) {
  __shared__ int sh[SCAN_B];
  int base = blockIdx.x * (SCAN_B * SCAN_E) + threadIdx.x * SCAN_E;
  int v[SCAN_E];
  int s = 0;
#pragma unroll
  for (int j = 0; j < SCAN_E; ++j) {
    v[j] = (base + j < n) ? deg[base + j] : 0;
    s += v[j];
  }
  sh[threadIdx.x] = s;
  __syncthreads();
  for (int off = 1; off < SCAN_B; off <<= 1) {
    int t = (threadIdx.x >= off) ? sh[threadIdx.x - off] : 0;
    __syncthreads();
    sh[threadIdx.x] += t;
    __syncthreads();
  }
  if (threadIdx.x == SCAN_B - 1) blksum[blockIdx.x] = sh[SCAN_B - 1];
  int run = sh[threadIdx.x] - s;
#pragma unroll
  for (int j = 0; j < SCAN_E; ++j) {
    if (base + j < n) rowptr[base + j] = run;
    run += v[j];
  }
}

__global__ void scan2_kernel(int* __restrict__ blksum, int nb) {
  __shared__ int sh[SCAN_B];
  int v = (threadIdx.x < nb) ? blksum[threadIdx.x] : 0;
  sh[threadIdx.x] = v;
  __syncthreads();
  for (int off = 1; off < SCAN_B; off <<= 1) {
    int t = (threadIdx.x >= off) ? sh[threadIdx.x - off] : 0;
    __syncthreads();
    sh[threadIdx.x] += t;
    __syncthreads();
  }
  if (threadIdx.x < nb) blksum[threadIdx.x] = sh[threadIdx.x] - v;
}

__global__ void scan3_kernel(int* __restrict__ rowptr, int* __restrict__ cursor,
                             const int* __restrict__ blksum, int n) {
  int i = blockIdx.x * blockDim.x + threadIdx.x;
  if (i >= n) return;
  int v = rowptr[i] + blksum[i / (SCAN_B * SCAN_E)];
  rowptr[i] = v;
  cursor[i] = v;
}

__global__ void scatter_kernel(const int* __restrict__ row, const int* __restrict__ col,
                               int* __restrict__ cursor, int* __restrict__ eslot,
                               int* __restrict__ ecol, int E) {
  int gid = blockIdx.x * blockDim.x + threadIdx.x;
  if (gid >= E) return;
  int r = row[gid];
  int slot = atomicAdd(&cursor[r], 1);
  eslot[gid] = slot;
  ecol[slot] = col[gid];
}

// One wave per row; 4 edges across lane groups x 2-deep manual unroll = 8 gathers
// in flight per wave.
__global__ void __launch_bounds__(256) row_attn_kernel(const float* __restrict__ escores,
    const int* __restrict__ rowptr, const int* __restrict__ deg,
    const int* __restrict__ ecol,
    const unsigned short* __restrict__ vb, float* __restrict__ hout, int n) {
  int gid = blockIdx.x * blockDim.x + threadIdx.x;
  int r = gid >> 6, lane = threadIdx.x & 63;
  if (r >= n) return;
  int gi = lane >> 4, j = lane & 15;
  int start = rowptr[r], dg = deg[r];

  f32x4 acc = (f32x4){0.f, 0.f, 0.f, 0.f};
  f32x4 den = (f32x4){0.f, 0.f, 0.f, 0.f};
  int i = gi;
  for (; i + 4 < dg; i += 8) {
    int ia = start + i, ib = start + i + 4;
    int ca = ecol[ia], cb = ecol[ib];
    f32x4 sa = *(const f32x4*)(escores + (size_t)ia * 8 + 4 * (j & 1));
    f32x4 sb = *(const f32x4*)(escores + (size_t)ib * 8 + 4 * (j & 1));
    u16x4 va = *(const u16x4*)(vb + (size_t)ca * 64 + j * 4);
    u16x4 vc = *(const u16x4*)(vb + (size_t)cb * 64 + j * 4);
#pragma unroll
    for (int m = 0; m < 4; ++m) {
      float ea = __expf(sa[m]);
      float eb = __expf(sb[m]);
      den[m] += ea + eb;
      acc[m] += ea * bf2f(va[m]) + eb * bf2f(vc[m]);
    }
  }
  if (i < dg) {
    int idx = start + i;
    int c = ecol[idx];
    f32x4 sv = *(const f32x4*)(escores + (size_t)idx * 8 + 4 * (j & 1));
    u16x4 vv = *(const u16x4*)(vb + (size_t)c * 64 + j * 4);
#pragma unroll
    for (int m = 0; m < 4; ++m) {
      float ex = __expf(sv[m]);
      den[m] += ex;
      acc[m] += ex * bf2f(vv[m]);
    }
  }
#pragma unroll
  for (int m = 0; m < 4; ++m) {
    acc[m] += __shfl_xor(acc[m], 16, 64);
    acc[m] += __shfl_xor(acc[m], 32, 64);
    den[m] += __shfl_xor(den[m], 16, 64);
    den[m] += __shfl_xor(den[m], 32, 64);
  }
  if (gi == 0) {
    f32x4 o;
#pragma unroll
    for (int m = 0; m < 4; ++m) o[m] = (dg > 0) ? acc[m] / den[m] : 0.f;
    *(f32x4*)(hout + (size_t)r * 64 + j * 4) = o;
  }
}

extern "C" void kernel_launch(void* const* d_in, const int* in_sizes, int n_in,
                              void* d_out, int out_size, void* d_ws, size_t ws_size,
                              hipStream_t stream) {
  const float* hx  = (const float*)d_in[0];
  const float* he  = (const float*)d_in[1];
  const int*   row = (const int*)d_in[2];
  const int*   col = (const int*)d_in[3];
  const float* Wq = (const float*)d_in[4],  *bq = (const float*)d_in[5];
  const float* Wk = (const float*)d_in[6],  *bk = (const float*)d_in[7];
  const float* Wv = (const float*)d_in[8],  *bv = (const float*)d_in[9];
  const float* We = (const float*)d_in[10], *be = (const float*)d_in[11];
  const float* Woh = (const float*)d_in[12], *boh = (const float*)d_in[13];
  const float* Woe = (const float*)d_in[14], *boe = (const float*)d_in[15];

  const int n = in_sizes[0] / 64;
  const int E = in_sizes[2];

  float* out = (float*)d_out;
  float* oh = out;                   // n*64 fp32
  float* oe = out + (size_t)n * 64;  // E*64 fp32

  // ws: qb,kb,vbuf (n*64 bf16) | escores (E*8 f32, CSR order) | hout (n*64 f32)
  //   | deg,rowptr,cursor (n int) | blksum (256) | eslot (E) | ecol (E) | WeM,beM
  unsigned short* qb   = (unsigned short*)d_ws;
  unsigned short* kb   = qb + (size_t)n * 64;
  unsigned short* vbuf = kb + (size_t)n * 64;
  float* escores = (float*)(vbuf + (size_t)n * 64);
  float* hout    = escores + (size_t)E * 8;

  int* deg    = (int*)(hout + (size_t)n * 64);
  int* rowptr = deg + n;
  int* cursor = rowptr + n;
  int* blksum = cursor + n;
  int* eslot  = blksum + 256;
  int* ecol   = eslot + (size_t)E;
  float* WeM  = (float*)(ecol + (size_t)E);
  float* beM  = WeM + 512;

  const int nb_scan = (n + SCAN_B * SCAN_E - 1) / (SCAN_B * SCAN_E);

  // CSR build (depends only on row/col)
  zero_kernel<<<(n + 255) / 256, 256, 0, stream>>>(deg, n);
  hist_kernel<<<(E + 255) / 256, 256, 0, stream>>>(row, deg, E);
  scan1_kernel<<<nb_scan, SCAN_B, 0, stream>>>(deg, rowptr, blksum, n);
  scan2_kernel<<<1, SCAN_B, 0, stream>>>(blksum, nb_scan);
  scan3_kernel<<<(n + 255) / 256, 256, 0, stream>>>(rowptr, cursor, blksum, n);
  scatter_kernel<<<(E + 255) / 256, 256, 0, stream>>>(row, col, cursor, eslot, ecol, E);

  qkv3_kernel<<<512, 256, 0, stream>>>(hx, Wq, bq, Wk, bk, Wv, bv, qb, kb, vbuf, n);
  wemprep_kernel<<<1, 512, 0, stream>>>(We, be, WeM, beM);

  edge_fused_kernel<<<2048, 256, 0, stream>>>(he, row, col, eslot, qb, kb,
                                              We, be, Woe, boe, WeM, beM,
                                              oe, escores, E);

  row_attn_kernel<<<(n + 3) / 4, 256, 0, stream>>>(escores, rowptr, deg, ecol,
                                                   vbuf, hout, n);
  gemm64_kernel<false, false><<<512, 256, 0, stream>>>(hout, Woh, boh, oh, n);
}